// Round 4
// baseline (102.441 us; speedup 1.0000x reference)
//
#include <hip/hip_runtime.h>
#include <stdint.h>

// ROUND 15b (compile fix: __builtin_nontemporal_store needs a native clang
// ext_vector type, not HIP's float2 class -> use f32x2 ext_vector).
// Same numerics recipe as R14 (DO NOT TOUCH — 13 rounds of elimination
// pinned it):
//   cur  = (x0*w10) + (x1*w11)        // NO fma: two rounded products, one add
//   rec  = m = fma(0.9f, m, cur); m = m - r;   // fused mul-add, separate sub
//   spk  = (m > 1.0f)                 // == (m-1 > 0) sign-exact (Sterbenz)
//   L2   = seq sum of exact products  // ((p0+p1)+p2)+p3
// Perf change only: VEC 4->2 (524,288 threads = 32 waves/CU, 2x TLP; R14's
// 262,144 threads half-filled the machine at 4 waves/SIMD and was
// store-latency bound at ~45 us vs a 14.7 us memory floor), plus
// __launch_bounds__(256,8) to hold VGPRs <= 64 for 8 waves/SIMD, plus
// nontemporal output stores (out is never re-read).

constexpr int T_STEPS = 20;
constexpr int H = 4;
constexpr int VEC = 2;   // batch elements per thread -> float4 x-load, 8B store

typedef float f32x2 __attribute__((ext_vector_type(2)));

__global__ __launch_bounds__(256, 8) void snn_r15_kernel(
    const float* __restrict__ x,    // f32 [B,2]
    const float* __restrict__ w1,   // f32 [4,2] row-major
    const float* __restrict__ w2,   // f32 [1,4]
    float* __restrict__ out,        // f32 [T,B]
    int B)
{
#pragma clang fp contract(off)
    const int tid = blockIdx.x * blockDim.x + threadIdx.x;
    if (tid * VEC >= B) return;

    float w1r[H][2], w2r[H];
#pragma unroll
    for (int h = 0; h < H; ++h) {
        w1r[h][0] = w1[2 * h];
        w1r[h][1] = w1[2 * h + 1];
        w2r[h]    = w2[h];
    }

    // One 16B load covers both batch elements: x[2*(2tid)..2*(2tid)+3]
    const float4 xa = reinterpret_cast<const float4*>(x)[tid];
    const float xv[VEC][2] = {{xa.x, xa.y}, {xa.z, xa.w}};

    float cur[VEC][H], m1[VEC][H], m2[VEC];
#pragma unroll
    for (int l = 0; l < VEC; ++l) {
#pragma unroll
        for (int h = 0; h < H; ++h) {
            // nofma dot: round both products, one add (commutative -> one variant)
            cur[l][h] = (xv[l][0] * w1r[h][0]) + (xv[l][1] * w1r[h][1]);
            m1[l][h] = 0.0f;
        }
        m2[l] = 0.0f;
    }

#pragma unroll
    for (int t = 0; t < T_STEPS; ++t) {
        f32x2 o;
#pragma unroll
        for (int l = 0; l < VEC; ++l) {
            float p[H];
#pragma unroll
            for (int h = 0; h < H; ++h) {
                float m = m1[l][h];
                const float r = (m > 1.0f) ? 1.0f : 0.0f;   // reset = prev spike
                m = fmaf(0.9f, m, cur[l][h]);               // fused mul-add
                m = m - r;                                  // separate subtract
                m1[l][h] = m;
                p[h] = (m > 1.0f) ? w2r[h] : 0.0f;          // s*w2, exact product
            }
            const float outv = ((p[0] + p[1]) + p[2]) + p[3];
            float m = m2[l];
            const float r = (m > 1.0f) ? 1.0f : 0.0f;
            m = fmaf(0.9f, m, outv);
            m = m - r;
            m2[l] = m;
            o[l] = (m > 1.0f) ? 1.0f : 0.0f;
        }
        // coalesced 8B/lane (512B per wave-store), streaming (never re-read)
        __builtin_nontemporal_store(
            o, reinterpret_cast<f32x2*>(out + (size_t)t * B) + tid);
    }
}

extern "C" void kernel_launch(void* const* d_in, const int* in_sizes, int n_in,
                              void* d_out, int out_size, void* d_ws, size_t ws_size,
                              hipStream_t stream) {
    const float* x  = (const float*)d_in[0];
    const float* w1 = (const float*)d_in[1];
    const float* w2 = (const float*)d_in[2];
    float* out = (float*)d_out;
    const int B = in_sizes[0] / 2;          // 1,048,576
    const int n_thr = B / VEC;              // 524,288 threads
    const int threads = 256;
    snn_r15_kernel<<<(n_thr + threads - 1) / threads, threads, 0, stream>>>(x, w1, w2, out, B);
}

// Round 6
// 97.439 us; speedup vs baseline: 1.0513x; 1.0513x over previous
//
#include <hip/hip_runtime.h>
#include <stdint.h>

// ROUND 16 (resubmit — R5 bench was an infra failure "container failed twice",
// kernel never ran). Discriminating experiment, VEC=1 (one element per thread).
// R15 (VEC=2 + 8-wave launch_bounds + nontemporal) was NEUTRAL vs R14
// (total 102.4 vs 97.6, ~2us of it fill drift) -> occupancy doubling did
// not move the kernel. Two live hypotheses:
//   H-latency: VEC=2 was pinned by the 64-VGPR cap (store-address remat),
//              and/or NT stores hurt; VEC=1 has ~35 live regs, true
//              8 waves/SIMD, shortest chains -> snn ~45 -> <=20us.
//   H-overhead: snn is already ~13-15us (near the 84MB write floor) and
//              (total - fill) is mostly fixed tiny-dispatch graph overhead
//              -> total stays ~97-102 and we are at the roofline.
// This kernel discriminates: regular stores (NT reverted), no min-wave
// launch_bounds pressure, max TLP (1,048,576 threads, 16 blocks/CU).
//
// Numerics recipe IDENTICAL per element to R14 (DO NOT TOUCH — 13 rounds
// of elimination pinned it):
//   cur  = (x0*w10) + (x1*w11)        // NO fma: two rounded products, one add
//   rec  = m = fma(0.9f, m, cur); m = m - r;   // fused mul-add, separate sub
//   spk  = (m > 1.0f)                 // == (m-1 > 0) sign-exact (Sterbenz)
//   L2   = seq sum of exact products  // ((p0+p1)+p2)+p3

constexpr int T_STEPS = 20;
constexpr int H = 4;

typedef float f32x2 __attribute__((ext_vector_type(2)));

__global__ __launch_bounds__(256) void snn_r16_kernel(
    const float* __restrict__ x,    // f32 [B,2]
    const float* __restrict__ w1,   // f32 [4,2] row-major
    const float* __restrict__ w2,   // f32 [1,4]
    float* __restrict__ out,        // f32 [T,B]
    int B)
{
#pragma clang fp contract(off)
    const int tid = blockIdx.x * blockDim.x + threadIdx.x;
    if (tid >= B) return;

    float w1r[H][2], w2r[H];
#pragma unroll
    for (int h = 0; h < H; ++h) {
        w1r[h][0] = w1[2 * h];
        w1r[h][1] = w1[2 * h + 1];
        w2r[h]    = w2[h];
    }

    // 8B coalesced load: x[2*tid], x[2*tid+1]
    const f32x2 xv = reinterpret_cast<const f32x2*>(x)[tid];

    float cur[H], m1[H], m2 = 0.0f;
#pragma unroll
    for (int h = 0; h < H; ++h) {
        // nofma dot: round both products, one add (commutative -> one variant)
        cur[h] = (xv[0] * w1r[h][0]) + (xv[1] * w1r[h][1]);
        m1[h] = 0.0f;
    }

#pragma unroll
    for (int t = 0; t < T_STEPS; ++t) {
        float p[H];
#pragma unroll
        for (int h = 0; h < H; ++h) {
            float m = m1[h];
            const float r = (m > 1.0f) ? 1.0f : 0.0f;   // reset = prev spike
            m = fmaf(0.9f, m, cur[h]);                  // fused mul-add
            m = m - r;                                  // separate subtract
            m1[h] = m;
            p[h] = (m > 1.0f) ? w2r[h] : 0.0f;          // s*w2, exact product
        }
        const float outv = ((p[0] + p[1]) + p[2]) + p[3];
        const float r2 = (m2 > 1.0f) ? 1.0f : 0.0f;
        m2 = fmaf(0.9f, m2, outv);
        m2 = m2 - r2;
        // coalesced 4B/lane (256B per wave-store), regular store path
        out[(size_t)t * B + tid] = (m2 > 1.0f) ? 1.0f : 0.0f;
    }
}

extern "C" void kernel_launch(void* const* d_in, const int* in_sizes, int n_in,
                              void* d_out, int out_size, void* d_ws, size_t ws_size,
                              hipStream_t stream) {
    const float* x  = (const float*)d_in[0];
    const float* w1 = (const float*)d_in[1];
    const float* w2 = (const float*)d_in[2];
    float* out = (float*)d_out;
    const int B = in_sizes[0] / 2;          // 1,048,576
    const int threads = 256;
    snn_r16_kernel<<<(B + threads - 1) / threads, threads, 0, stream>>>(x, w1, w2, out, B);
}